// Round 11
// baseline (436.276 us; speedup 1.0000x reference)
//
#include <hip/hip_runtime.h>

// ---------------------------------------------------------------------------
// 3-layer GCN. Factorized: tmp[n] = dinv[n]*(h[n]@W); agg[i]=dinv[i]*(tmp[i]+sum tmp[src])+b
// All fp32 (threshold ~1e-5 relative of max|out|~488; bf16 forbidden).
// GEMM v9 = v2 tiling (4x4/thread, 1563-block grid: TLP wins over LDS ratio,
// R2-vs-R10) + DOUBLE-BUFFERED LDS: regs for chunk k+1 issued before compute
// of chunk k, one barrier/chunk (was 2). Attacks the K-independent per-chunk
// latency that keeps GEMM2 at ~2x its 31us LDS wall.
// AGG: padded branch-free 8-deep gather (R10), per-layer dummy remap.
// ---------------------------------------------------------------------------

// ---------------- CSR build ----------------

__global__ __launch_bounds__(256) void count_kernel(const int* __restrict__ dst,
                                                    int* __restrict__ cnt, int E) {
    int e = blockIdx.x * 256 + threadIdx.x;
    if (e < E) atomicAdd(&cnt[dst[e]], 1);
}

// dinv from true degree; padded count for CSR layout
__global__ __launch_bounds__(256) void dinv_kernel(const int* __restrict__ cnt,
                                                   float* __restrict__ dinv,
                                                   int* __restrict__ pcnt, int M) {
    int i = blockIdx.x * 256 + threadIdx.x;
    if (i < M) {
        int c = cnt[i];
        dinv[i] = 1.0f / sqrtf((float)c + 1.0f);  // +1: self-loop
        pcnt[i] = (c + 7) & ~7;
    }
}

__global__ __launch_bounds__(256) void srcs_fill_kernel(int* __restrict__ srcs,
                                                        int val, int n) {
    int i = blockIdx.x * 256 + threadIdx.x;
    if (i < n) srcs[i] = val;
}

// block-local exclusive scan of pcnt -> loc; per-block total -> bsum
__global__ __launch_bounds__(256) void scan1_kernel(const int* __restrict__ pcnt,
                                                    int* __restrict__ loc,
                                                    int* __restrict__ bsum, int M) {
    __shared__ int sm[256];
    int t = threadIdx.x;
    int i = blockIdx.x * 256 + t;
    int v = (i < M) ? pcnt[i] : 0;
    sm[t] = v;
    __syncthreads();
    for (int o = 1; o < 256; o <<= 1) {
        int add = (t >= o) ? sm[t - o] : 0;
        __syncthreads();
        sm[t] += add;
        __syncthreads();
    }
    if (i < M) loc[i] = sm[t] - v;
    if (t == 255) bsum[blockIdx.x] = sm[255];
}

__global__ __launch_bounds__(256) void scan2_kernel(int* __restrict__ bsum, int NB) {
    __shared__ int sm[256];
    int t = threadIdx.x;
    int v = (t < NB) ? bsum[t] : 0;
    sm[t] = v;
    __syncthreads();
    for (int o = 1; o < 256; o <<= 1) {
        int add = (t >= o) ? sm[t - o] : 0;
        __syncthreads();
        sm[t] += add;
        __syncthreads();
    }
    if (t < NB) bsum[t] = sm[t] - v;
}

__global__ __launch_bounds__(256) void place_kernel(const int* __restrict__ src,
                                                    const int* __restrict__ dst,
                                                    const int* __restrict__ loc,
                                                    const int* __restrict__ base,
                                                    int* __restrict__ fill,
                                                    int* __restrict__ srcs, int E) {
    int e = blockIdx.x * 256 + threadIdx.x;
    if (e >= E) return;
    int d = dst[e];
    int pos = loc[d] + base[d >> 8] + atomicAdd(&fill[d], 1);
    srcs[pos] = src[e];
}

// ---------------- GEMM v9 (v2 + LDS double-buffer) ----------------
// out[m][c] = dinv[m] * sum_k A[m][k]*W[k][c]

template <int K, int C>
__global__ __launch_bounds__(256) void gemm_scale_kernel(const float* __restrict__ A,
                                                         const float* __restrict__ W,
                                                         const float* __restrict__ dinv,
                                                         float* __restrict__ out, int M) {
    constexpr int CT = C / 4;         // threads across columns (each owns 4 cols)
    constexpr int RT = 256 / CT;      // thread rows (each owns 4 rows)
    constexpr int TM = RT * 4;        // rows per block (32 @C=128, 64 @C=64)
    constexpr int KB = 32;            // k-chunk
    constexpr int AP = TM + 4;        // padded row stride (16B-aligned, breaks pow2)
    constexpr int NCH = K / KB;
    constexpr int ALOADS = (TM * KB) / (256 * 4);  // float4 A loads/thread (1 or 2)
    constexpr int BLOADS = (KB * C) / (256 * 4);   // float4 W loads/thread (4 or 2)

    __shared__ __align__(16) float Ast[2][KB][AP];  // A tile, transposed
    __shared__ __align__(16) float Bs[2][KB][C];

    const int t = threadIdx.x;
    const int tx = t % CT;
    const int ty = t / CT;
    const int row0 = blockIdx.x * TM;

    float4 aReg[ALOADS], wReg[BLOADS];

    auto loadRegs = [&](int ch) {
        const int k0 = ch * KB;
#pragma unroll
        for (int l = 0; l < ALOADS; l++) {
            int idx = t + l * 256;
            int ar = idx >> 3;            // row within tile (8 float4 per 32-k row)
            int kq = (idx & 7) * 4;       // k offset
            int grow = row0 + ar;
            float4 v = make_float4(0.f, 0.f, 0.f, 0.f);
            if (grow < M) v = *(const float4*)(A + (size_t)grow * K + k0 + kq);
            aReg[l] = v;
        }
#pragma unroll
        for (int l = 0; l < BLOADS; l++) {
            int idx = t + l * 256;
            int bk = idx / (C / 4);
            int bc = (idx % (C / 4)) * 4;
            wReg[l] = *(const float4*)(W + (size_t)(k0 + bk) * C + bc);
        }
    };

    auto writeLDS = [&](int buf) {
#pragma unroll
        for (int l = 0; l < ALOADS; l++) {
            int idx = t + l * 256;
            int ar = idx >> 3;
            int kq = (idx & 7) * 4;
            Ast[buf][kq + 0][ar] = aReg[l].x;
            Ast[buf][kq + 1][ar] = aReg[l].y;
            Ast[buf][kq + 2][ar] = aReg[l].z;
            Ast[buf][kq + 3][ar] = aReg[l].w;
        }
#pragma unroll
        for (int l = 0; l < BLOADS; l++) {
            int idx = t + l * 256;
            int bk = idx / (C / 4);
            int bc = (idx % (C / 4)) * 4;
            *(float4*)(&Bs[buf][bk][bc]) = wReg[l];
        }
    };

    float acc[4][4];
#pragma unroll
    for (int i = 0; i < 4; i++)
#pragma unroll
        for (int j = 0; j < 4; j++) acc[i][j] = 0.f;

    loadRegs(0);

    for (int ch = 0; ch < NCH; ++ch) {
        const int buf = ch & 1;
        writeLDS(buf);                      // waits on this chunk's global loads
        __syncthreads();                    // writes visible; prev buf free
        if (ch + 1 < NCH) loadRegs(ch + 1); // in flight during compute below
#pragma unroll
        for (int k = 0; k < KB; k++) {
            float4 a = *(const float4*)(&Ast[buf][k][ty * 4]);
            float4 b = *(const float4*)(&Bs[buf][k][tx * 4]);
            acc[0][0] += a.x * b.x; acc[0][1] += a.x * b.y; acc[0][2] += a.x * b.z; acc[0][3] += a.x * b.w;
            acc[1][0] += a.y * b.x; acc[1][1] += a.y * b.y; acc[1][2] += a.y * b.z; acc[1][3] += a.y * b.w;
            acc[2][0] += a.z * b.x; acc[2][1] += a.z * b.y; acc[2][2] += a.z * b.z; acc[2][3] += a.z * b.w;
            acc[3][0] += a.w * b.x; acc[3][1] += a.w * b.y; acc[3][2] += a.w * b.z; acc[3][3] += a.w * b.w;
        }
        // no second barrier: next iter writes the OTHER buffer; the single
        // barrier at iter ch+1 orders those writes against all readers.
    }

#pragma unroll
    for (int i = 0; i < 4; i++) {
        int r = row0 + ty * 4 + i;
        if (r < M) {
            float dv = dinv[r];
            float4 v = make_float4(acc[i][0] * dv, acc[i][1] * dv, acc[i][2] * dv, acc[i][3] * dv);
            *(float4*)(out + (size_t)r * C + tx * 4) = v;
        }
    }
}

// ---------------- Aggregation: out[i] = act(dinv[i]*(tmp[i] + sum tmp[src]) + b) ----------------
// Padded edge lists (multiple of 8): branch-free 8-deep gather pipeline.
// Dummy entries hold value M in srcs; remapped to DUMMY (per-layer index of
// the zeroed row under this layer's stride).

template <int C, bool RELU>
__global__ __launch_bounds__(256) void agg_kernel(const float* __restrict__ tmp,
                                                  const int* __restrict__ srcs,
                                                  const int* __restrict__ pcnt,
                                                  const int* __restrict__ loc,
                                                  const int* __restrict__ base,
                                                  const float* __restrict__ dinv,
                                                  const float* __restrict__ bias,
                                                  float* __restrict__ out,
                                                  int M, int DUMMY) {
    constexpr int TPN = C / 4;        // threads per node (float4 per thread)
    constexpr int NPB = 256 / TPN;    // nodes per block
    const int t = threadIdx.x;
    const int cq = t % TPN;
    const int node = blockIdx.x * NPB + t / TPN;
    if (node >= M) return;

    const float4* tmp4 = (const float4*)tmp;
    float4 acc = tmp4[(size_t)node * TPN + cq];   // self-loop term
    float4 acc2 = make_float4(0.f, 0.f, 0.f, 0.f);
    const int start = loc[node] + base[node >> 8];
    const int pn = pcnt[node];                    // multiple of 8
    const int* sp = srcs + start;                 // 32B-aligned (start % 8 == 0)

    auto remap = [&](int4& v) {
        v.x = v.x < M ? v.x : DUMMY;
        v.y = v.y < M ? v.y : DUMMY;
        v.z = v.z < M ? v.z : DUMMY;
        v.w = v.w < M ? v.w : DUMMY;
    };

    int4 ia, ib;
    if (pn > 0) {
        ia = *(const int4*)(sp); ib = *(const int4*)(sp + 4);
        remap(ia); remap(ib);
    }
    for (int j = 0; j < pn; j += 8) {
        float4 v0 = tmp4[(size_t)ia.x * TPN + cq];
        float4 v1 = tmp4[(size_t)ia.y * TPN + cq];
        float4 v2 = tmp4[(size_t)ia.z * TPN + cq];
        float4 v3 = tmp4[(size_t)ia.w * TPN + cq];
        float4 v4 = tmp4[(size_t)ib.x * TPN + cq];
        float4 v5 = tmp4[(size_t)ib.y * TPN + cq];
        float4 v6 = tmp4[(size_t)ib.z * TPN + cq];
        float4 v7 = tmp4[(size_t)ib.w * TPN + cq];
        if (j + 8 < pn) {
            ia = *(const int4*)(sp + j + 8);
            ib = *(const int4*)(sp + j + 12);
            remap(ia); remap(ib);
        }
        acc.x  += v0.x + v1.x;  acc.y  += v0.y + v1.y;
        acc.z  += v0.z + v1.z;  acc.w  += v0.w + v1.w;
        acc2.x += v2.x + v3.x;  acc2.y += v2.y + v3.y;
        acc2.z += v2.z + v3.z;  acc2.w += v2.w + v3.w;
        acc.x  += v4.x + v5.x;  acc.y  += v4.y + v5.y;
        acc.z  += v4.z + v5.z;  acc.w  += v4.w + v5.w;
        acc2.x += v6.x + v7.x;  acc2.y += v6.y + v7.y;
        acc2.z += v6.z + v7.z;  acc2.w += v6.w + v7.w;
    }
    acc.x += acc2.x; acc.y += acc2.y; acc.z += acc2.z; acc.w += acc2.w;

    float dv = dinv[node];
    float4 b = *(const float4*)(bias + cq * 4);
    float4 r;
    r.x = acc.x * dv + b.x;
    r.y = acc.y * dv + b.y;
    r.z = acc.z * dv + b.z;
    r.w = acc.w * dv + b.w;
    if (RELU) {
        r.x = fmaxf(r.x, 0.f); r.y = fmaxf(r.y, 0.f);
        r.z = fmaxf(r.z, 0.f); r.w = fmaxf(r.w, 0.f);
    }
    ((float4*)out)[(size_t)node * TPN + cq] = r;
}

// ---------------- launch ----------------

extern "C" void kernel_launch(void* const* d_in, const int* in_sizes, int n_in,
                              void* d_out, int out_size, void* d_ws, size_t ws_size,
                              hipStream_t stream) {
    const float* x  = (const float*)d_in[0];
    const int*   ei = (const int*)d_in[1];
    const float* W1 = (const float*)d_in[2];
    const float* b1 = (const float*)d_in[3];
    const float* W2 = (const float*)d_in[4];
    const float* b2 = (const float*)d_in[5];
    const float* W3 = (const float*)d_in[6];
    const float* b3 = (const float*)d_in[7];
    float* out = (float*)d_out;

    const int M = in_sizes[0] / 256;   // 50000 nodes
    const int E = in_sizes[1] / 2;     // 800000 edges
    const int NB = (M + 255) / 256;
    const int SRCN = E + 8 * M;        // padded srcs upper bound

    char* p = (char*)d_ws;
    auto alloc = [&](size_t bytes) {
        char* r = p;
        p += (bytes + 255) & ~(size_t)255;
        return r;
    };
    int*   cnt  = (int*)alloc((size_t)M * 4);
    int*   pcnt = (int*)alloc((size_t)M * 4);
    int*   fill = (int*)alloc((size_t)M * 4);
    int*   loc  = (int*)alloc((size_t)M * 4);
    int*   base = (int*)alloc((size_t)NB * 4);
    float* dinv = (float*)alloc((size_t)M * 4);
    int*   srcs = (int*)alloc((size_t)SRCN * 4);
    float* tmp  = (float*)alloc((size_t)(M + 1) * 128 * 4);  // +1: zero dummy row
    float* h    = (float*)alloc((size_t)M * 128 * 4);

    hipMemsetAsync(cnt, 0, (size_t)M * 4, stream);
    hipMemsetAsync(fill, 0, (size_t)M * 4, stream);
    // zero dummy region at float offset M*128: row M under stride 128 (C=128
    // layers) AND row 2M under stride 64 (C=64 layer) -> same bytes.
    hipMemsetAsync(tmp + (size_t)M * 128, 0, 128 * 4, stream);

    const int* esrc = ei;
    const int* edst = ei + E;

    count_kernel<<<(E + 255) / 256, 256, 0, stream>>>(edst, cnt, E);
    dinv_kernel<<<(M + 255) / 256, 256, 0, stream>>>(cnt, dinv, pcnt, M);
    scan1_kernel<<<NB, 256, 0, stream>>>(pcnt, loc, base, M);
    scan2_kernel<<<1, 256, 0, stream>>>(base, NB);
    srcs_fill_kernel<<<(SRCN + 255) / 256, 256, 0, stream>>>(srcs, M, SRCN);
    place_kernel<<<(E + 255) / 256, 256, 0, stream>>>(esrc, edst, loc, base, fill, srcs, E);

    // layer 1: x[50000,256] @ W1[256,128] -> relu agg -> h
    gemm_scale_kernel<256, 128><<<(M + 31) / 32, 256, 0, stream>>>(x, W1, dinv, tmp, M);
    agg_kernel<128, true><<<(M + 7) / 8, 256, 0, stream>>>(tmp, srcs, pcnt, loc, base, dinv, b1, h, M, M);

    // layer 2: h @ W2[128,128] -> relu agg -> h
    gemm_scale_kernel<128, 128><<<(M + 31) / 32, 256, 0, stream>>>(h, W2, dinv, tmp, M);
    agg_kernel<128, true><<<(M + 7) / 8, 256, 0, stream>>>(tmp, srcs, pcnt, loc, base, dinv, b2, h, M, M);

    // layer 3: h @ W3[128,64] -> agg -> out  (dummy row index 2M under stride 64)
    gemm_scale_kernel<128, 64><<<(M + 63) / 64, 256, 0, stream>>>(h, W3, dinv, tmp, M);
    agg_kernel<64, false><<<(M + 15) / 16, 256, 0, stream>>>(tmp, srcs, pcnt, loc, base, dinv, b3, out, M, 2 * M);
}

// Round 12
// 339.478 us; speedup vs baseline: 1.2851x; 1.2851x over previous
//
#include <hip/hip_runtime.h>

// ---------------------------------------------------------------------------
// 3-layer GCN. Factorized: tmp[n] = dinv[n]*(h[n]@W); agg[i]=dinv[i]*(tmp[i]+sum tmp[src])+b
// All fp32 (threshold ~1e-5 relative of max|out|~488; bf16 forbidden).
// GEMM: v2 (proven optimal over 6 experiments) -- at the fp32 LDS-instruction
//   wall: 2 ds_read_b128/k/wave x 12cyc vs 32 VALU-cyc, 4 SIMDs share 1 LDS
//   pipe -> f=1/3 of peak = 62us GEMM1 (measured 62.4). Bigger tiles lose to
//   VGPR/occupancy (v5-v8,v11); reg-staging dbuf loses occupancy (v11).
// AGG: padded branch-free 8-deep gather (R10), per-layer dummy remap; at the
//   ~3 TB/s random-gather L2-fill rate.
// R12: CSR slimming only -- dinv fused into scan1; tail-pad (<=7 writes/node)
//   replaces the 1.25M-entry srcs_fill.
// ---------------------------------------------------------------------------

// ---------------- CSR build ----------------

__global__ __launch_bounds__(256) void count_kernel(const int* __restrict__ dst,
                                                    int* __restrict__ cnt, int E) {
    int e = blockIdx.x * 256 + threadIdx.x;
    if (e < E) atomicAdd(&cnt[dst[e]], 1);
}

// fused: dinv + padded count + block-local exclusive scan of pcnt
__global__ __launch_bounds__(256) void scan1_dinv_kernel(const int* __restrict__ cnt,
                                                         float* __restrict__ dinv,
                                                         int* __restrict__ pcnt,
                                                         int* __restrict__ loc,
                                                         int* __restrict__ bsum, int M) {
    __shared__ int sm[256];
    int t = threadIdx.x;
    int i = blockIdx.x * 256 + t;
    int c = (i < M) ? cnt[i] : 0;
    int v = (c + 7) & ~7;
    if (i < M) {
        dinv[i] = 1.0f / sqrtf((float)c + 1.0f);  // +1: self-loop
        pcnt[i] = v;
    }
    sm[t] = v;
    __syncthreads();
    for (int o = 1; o < 256; o <<= 1) {
        int add = (t >= o) ? sm[t - o] : 0;
        __syncthreads();
        sm[t] += add;
        __syncthreads();
    }
    if (i < M) loc[i] = sm[t] - v;
    if (t == 255) bsum[blockIdx.x] = sm[255];
}

__global__ __launch_bounds__(256) void scan2_kernel(int* __restrict__ bsum, int NB) {
    __shared__ int sm[256];
    int t = threadIdx.x;
    int v = (t < NB) ? bsum[t] : 0;
    sm[t] = v;
    __syncthreads();
    for (int o = 1; o < 256; o <<= 1) {
        int add = (t >= o) ? sm[t - o] : 0;
        __syncthreads();
        sm[t] += add;
        __syncthreads();
    }
    if (t < NB) bsum[t] = sm[t] - v;
}

// write only the dummy tail slots (cnt[i]..pcnt[i]) of each node's edge list
__global__ __launch_bounds__(256) void pad_tail_kernel(const int* __restrict__ cnt,
                                                       const int* __restrict__ pcnt,
                                                       const int* __restrict__ loc,
                                                       const int* __restrict__ base,
                                                       int* __restrict__ srcs,
                                                       int M, int DUMMYV) {
    int i = blockIdx.x * 256 + threadIdx.x;
    if (i >= M) return;
    int start = loc[i] + base[i >> 8];
    int c = cnt[i], pn = pcnt[i];
    for (int j = c; j < pn; ++j) srcs[start + j] = DUMMYV;
}

__global__ __launch_bounds__(256) void place_kernel(const int* __restrict__ src,
                                                    const int* __restrict__ dst,
                                                    const int* __restrict__ loc,
                                                    const int* __restrict__ base,
                                                    int* __restrict__ fill,
                                                    int* __restrict__ srcs, int E) {
    int e = blockIdx.x * 256 + threadIdx.x;
    if (e >= E) return;
    int d = dst[e];
    int pos = loc[d] + base[d >> 8] + atomicAdd(&fill[d], 1);
    srcs[pos] = src[e];
}

// ---------------- GEMM (v2, proven): out[m][c] = dinv[m] * sum_k A[m][k]*W[k][c] ----

template <int K, int C>
__global__ __launch_bounds__(256) void gemm_scale_kernel(const float* __restrict__ A,
                                                         const float* __restrict__ W,
                                                         const float* __restrict__ dinv,
                                                         float* __restrict__ out, int M) {
    constexpr int CT = C / 4;         // threads across columns (each owns 4 cols)
    constexpr int RT = 256 / CT;      // thread rows (each owns 4 rows)
    constexpr int TM = RT * 4;        // rows per block
    constexpr int KB = 32;            // k-chunk
    constexpr int AP = TM + 4;        // padded row stride (16B-aligned, breaks pow2)

    __shared__ __align__(16) float Ast[KB][AP];   // A tile, transposed: Ast[k][row]
    __shared__ __align__(16) float Bs[KB][C];

    const int t = threadIdx.x;
    const int tx = t % CT;
    const int ty = t / CT;
    const int row0 = blockIdx.x * TM;

    float acc[4][4];
#pragma unroll
    for (int i = 0; i < 4; i++)
#pragma unroll
        for (int j = 0; j < 4; j++) acc[i][j] = 0.f;

    constexpr int ALOADS = (TM * KB) / (256 * 4);  // float4 loads of A per thread
    constexpr int BLOADS = (KB * C) / (256 * 4);   // float4 loads of W per thread

    for (int k0 = 0; k0 < K; k0 += KB) {
#pragma unroll
        for (int l = 0; l < ALOADS; l++) {
            int idx = t + l * 256;
            int ar = idx >> 3;            // row within tile (8 float4 per 32-k row)
            int kq = (idx & 7) * 4;       // k offset
            int grow = row0 + ar;
            float4 v = make_float4(0.f, 0.f, 0.f, 0.f);
            if (grow < M) v = *(const float4*)(A + (size_t)grow * K + k0 + kq);
            Ast[kq + 0][ar] = v.x;
            Ast[kq + 1][ar] = v.y;
            Ast[kq + 2][ar] = v.z;
            Ast[kq + 3][ar] = v.w;
        }
#pragma unroll
        for (int l = 0; l < BLOADS; l++) {
            int idx = t + l * 256;
            int bk = idx / (C / 4);
            int bc = (idx % (C / 4)) * 4;
            *(float4*)(&Bs[bk][bc]) = *(const float4*)(W + (size_t)(k0 + bk) * C + bc);
        }
        __syncthreads();
#pragma unroll
        for (int k = 0; k < KB; k++) {
            float4 a = *(const float4*)(&Ast[k][ty * 4]);
            float4 b = *(const float4*)(&Bs[k][tx * 4]);
            acc[0][0] += a.x * b.x; acc[0][1] += a.x * b.y; acc[0][2] += a.x * b.z; acc[0][3] += a.x * b.w;
            acc[1][0] += a.y * b.x; acc[1][1] += a.y * b.y; acc[1][2] += a.y * b.z; acc[1][3] += a.y * b.w;
            acc[2][0] += a.z * b.x; acc[2][1] += a.z * b.y; acc[2][2] += a.z * b.z; acc[2][3] += a.z * b.w;
            acc[3][0] += a.w * b.x; acc[3][1] += a.w * b.y; acc[3][2] += a.w * b.z; acc[3][3] += a.w * b.w;
        }
        __syncthreads();
    }
#pragma unroll
    for (int i = 0; i < 4; i++) {
        int r = row0 + ty * 4 + i;
        if (r < M) {
            float dv = dinv[r];
            float4 v = make_float4(acc[i][0] * dv, acc[i][1] * dv, acc[i][2] * dv, acc[i][3] * dv);
            *(float4*)(out + (size_t)r * C + tx * 4) = v;
        }
    }
}

// ---------------- Aggregation: out[i] = act(dinv[i]*(tmp[i] + sum tmp[src]) + b) ----------------
// Padded edge lists (multiple of 8): branch-free 8-deep gather pipeline.
// Dummy entries hold value M in srcs; remapped to DUMMY (per-layer index of
// the zeroed row under this layer's stride).

template <int C, bool RELU>
__global__ __launch_bounds__(256) void agg_kernel(const float* __restrict__ tmp,
                                                  const int* __restrict__ srcs,
                                                  const int* __restrict__ pcnt,
                                                  const int* __restrict__ loc,
                                                  const int* __restrict__ base,
                                                  const float* __restrict__ dinv,
                                                  const float* __restrict__ bias,
                                                  float* __restrict__ out,
                                                  int M, int DUMMY) {
    constexpr int TPN = C / 4;        // threads per node (float4 per thread)
    constexpr int NPB = 256 / TPN;    // nodes per block
    const int t = threadIdx.x;
    const int cq = t % TPN;
    const int node = blockIdx.x * NPB + t / TPN;
    if (node >= M) return;

    const float4* tmp4 = (const float4*)tmp;
    float4 acc = tmp4[(size_t)node * TPN + cq];   // self-loop term
    float4 acc2 = make_float4(0.f, 0.f, 0.f, 0.f);
    const int start = loc[node] + base[node >> 8];
    const int pn = pcnt[node];                    // multiple of 8
    const int* sp = srcs + start;                 // 32B-aligned (start % 8 == 0)

    auto remap = [&](int4& v) {
        v.x = v.x < M ? v.x : DUMMY;
        v.y = v.y < M ? v.y : DUMMY;
        v.z = v.z < M ? v.z : DUMMY;
        v.w = v.w < M ? v.w : DUMMY;
    };

    int4 ia, ib;
    if (pn > 0) {
        ia = *(const int4*)(sp); ib = *(const int4*)(sp + 4);
        remap(ia); remap(ib);
    }
    for (int j = 0; j < pn; j += 8) {
        float4 v0 = tmp4[(size_t)ia.x * TPN + cq];
        float4 v1 = tmp4[(size_t)ia.y * TPN + cq];
        float4 v2 = tmp4[(size_t)ia.z * TPN + cq];
        float4 v3 = tmp4[(size_t)ia.w * TPN + cq];
        float4 v4 = tmp4[(size_t)ib.x * TPN + cq];
        float4 v5 = tmp4[(size_t)ib.y * TPN + cq];
        float4 v6 = tmp4[(size_t)ib.z * TPN + cq];
        float4 v7 = tmp4[(size_t)ib.w * TPN + cq];
        if (j + 8 < pn) {
            ia = *(const int4*)(sp + j + 8);
            ib = *(const int4*)(sp + j + 12);
            remap(ia); remap(ib);
        }
        acc.x  += v0.x + v1.x;  acc.y  += v0.y + v1.y;
        acc.z  += v0.z + v1.z;  acc.w  += v0.w + v1.w;
        acc2.x += v2.x + v3.x;  acc2.y += v2.y + v3.y;
        acc2.z += v2.z + v3.z;  acc2.w += v2.w + v3.w;
        acc.x  += v4.x + v5.x;  acc.y  += v4.y + v5.y;
        acc.z  += v4.z + v5.z;  acc.w  += v4.w + v5.w;
        acc2.x += v6.x + v7.x;  acc2.y += v6.y + v7.y;
        acc2.z += v6.z + v7.z;  acc2.w += v6.w + v7.w;
    }
    acc.x += acc2.x; acc.y += acc2.y; acc.z += acc2.z; acc.w += acc2.w;

    float dv = dinv[node];
    float4 b = *(const float4*)(bias + cq * 4);
    float4 r;
    r.x = acc.x * dv + b.x;
    r.y = acc.y * dv + b.y;
    r.z = acc.z * dv + b.z;
    r.w = acc.w * dv + b.w;
    if (RELU) {
        r.x = fmaxf(r.x, 0.f); r.y = fmaxf(r.y, 0.f);
        r.z = fmaxf(r.z, 0.f); r.w = fmaxf(r.w, 0.f);
    }
    ((float4*)out)[(size_t)node * TPN + cq] = r;
}

// ---------------- launch ----------------

extern "C" void kernel_launch(void* const* d_in, const int* in_sizes, int n_in,
                              void* d_out, int out_size, void* d_ws, size_t ws_size,
                              hipStream_t stream) {
    const float* x  = (const float*)d_in[0];
    const int*   ei = (const int*)d_in[1];
    const float* W1 = (const float*)d_in[2];
    const float* b1 = (const float*)d_in[3];
    const float* W2 = (const float*)d_in[4];
    const float* b2 = (const float*)d_in[5];
    const float* W3 = (const float*)d_in[6];
    const float* b3 = (const float*)d_in[7];
    float* out = (float*)d_out;

    const int M = in_sizes[0] / 256;   // 50000 nodes
    const int E = in_sizes[1] / 2;     // 800000 edges
    const int NB = (M + 255) / 256;
    const int SRCN = E + 8 * M;        // padded srcs upper bound

    char* p = (char*)d_ws;
    auto alloc = [&](size_t bytes) {
        char* r = p;
        p += (bytes + 255) & ~(size_t)255;
        return r;
    };
    int*   cnt  = (int*)alloc((size_t)M * 4);
    int*   pcnt = (int*)alloc((size_t)M * 4);
    int*   fill = (int*)alloc((size_t)M * 4);
    int*   loc  = (int*)alloc((size_t)M * 4);
    int*   base = (int*)alloc((size_t)NB * 4);
    float* dinv = (float*)alloc((size_t)M * 4);
    int*   srcs = (int*)alloc((size_t)SRCN * 4);
    float* tmp  = (float*)alloc((size_t)(M + 1) * 128 * 4);  // +1: zero dummy row
    float* h    = (float*)alloc((size_t)M * 128 * 4);

    hipMemsetAsync(cnt, 0, (size_t)M * 4, stream);
    hipMemsetAsync(fill, 0, (size_t)M * 4, stream);
    // zero dummy region at float offset M*128: row M under stride 128 (C=128
    // layers) AND row 2M under stride 64 (C=64 layer) -> same bytes.
    hipMemsetAsync(tmp + (size_t)M * 128, 0, 128 * 4, stream);

    const int* esrc = ei;
    const int* edst = ei + E;

    count_kernel<<<(E + 255) / 256, 256, 0, stream>>>(edst, cnt, E);
    scan1_dinv_kernel<<<NB, 256, 0, stream>>>(cnt, dinv, pcnt, loc, base, M);
    scan2_kernel<<<1, 256, 0, stream>>>(base, NB);
    pad_tail_kernel<<<NB, 256, 0, stream>>>(cnt, pcnt, loc, base, srcs, M, M);
    place_kernel<<<(E + 255) / 256, 256, 0, stream>>>(esrc, edst, loc, base, fill, srcs, E);

    // layer 1: x[50000,256] @ W1[256,128] -> relu agg -> h
    gemm_scale_kernel<256, 128><<<(M + 31) / 32, 256, 0, stream>>>(x, W1, dinv, tmp, M);
    agg_kernel<128, true><<<(M + 7) / 8, 256, 0, stream>>>(tmp, srcs, pcnt, loc, base, dinv, b1, h, M, M);

    // layer 2: h @ W2[128,128] -> relu agg -> h
    gemm_scale_kernel<128, 128><<<(M + 31) / 32, 256, 0, stream>>>(h, W2, dinv, tmp, M);
    agg_kernel<128, true><<<(M + 7) / 8, 256, 0, stream>>>(tmp, srcs, pcnt, loc, base, dinv, b2, h, M, M);

    // layer 3: h @ W3[128,64] -> agg -> out  (dummy row index 2M under stride 64)
    gemm_scale_kernel<128, 64><<<(M + 63) / 64, 256, 0, stream>>>(h, W3, dinv, tmp, M);
    agg_kernel<64, false><<<(M + 15) / 16, 256, 0, stream>>>(tmp, srcs, pcnt, loc, base, dinv, b3, out, M, 2 * M);
}